// Round 9
// baseline (232.550 us; speedup 1.0000x reference)
//
#include <hip/hip_runtime.h>

#define N_    64
#define HW_   240
#define H1_   120
#define H2_   60
#define C0_   3
#define C1_   32
#define C2_   64
#define C3_   128
#define HEAD_ 1280

typedef unsigned short US;
typedef short bf16x8 __attribute__((ext_vector_type(8)));
typedef float f32x16 __attribute__((ext_vector_type(16)));

__device__ __forceinline__ US f2bf(float f) {
  union { float f; unsigned u; } v; v.f = f;
  unsigned r = v.u + 0x7FFF + ((v.u >> 16) & 1);  // RNE
  return (US)(r >> 16);
}

// h1q parity-split padded NHWC bf16: [n][row 122][parity 2][xh 62][32ch].
// h1 pixel (gy,gx): row = gy+1; gx even=2m -> plane0[m]; gx odd=2m-1 -> plane1[m].
// Row stride 3968 elems; plane stride 1984.
#define H1Q_ROW 3968
#define H1Q_PL  1984

// ---------------------------------------------------------------------------
// K0: prep — zero exactly the h1q cells k2 reads but k1 doesn't write
// (rows 0/121 fully; p1 m=0 for rows 1..120) with uint4 stores;
// w1 -> wt1 [ky][kx][oc][ic] bf16; w2 -> wt2 [oc][ic] bf16; zero gap.
// ---------------------------------------------------------------------------
#define ZCHN   368                 // zero-chunks per n (124+124+120)
#define ZTOT   (64 * ZCHN * 4)     // uint4 stores total = 94208
__global__ __launch_bounds__(256) void k0_prep(
    const float* __restrict__ w1, const float* __restrict__ w2,
    US* __restrict__ h1q, US* __restrict__ wt1, US* __restrict__ wt2,
    float* __restrict__ gap) {
  int gid = blockIdx.x * 256 + threadIdx.x;
  if (gid < ZTOT) {
    int c = gid >> 2, q = gid & 3;
    int n = c / ZCHN, cc = c % ZCHN;
    long off; int y;
    if (cc < 124)      { y = 0;   off = (long)cc * 32; }
    else if (cc < 248) { y = 121; off = (long)(cc - 124) * 32; }
    else               { y = cc - 247; off = H1Q_PL; }   // p1 m=0, rows 1..120
    uint4 z; z.x = z.y = z.z = z.w = 0u;
    *(uint4*)(h1q + ((long)(n * 122 + y)) * H1Q_ROW + off + q * 8) = z;
  } else if (gid < ZTOT + 18432) {
    int e = gid - ZTOT;                       // w1 flat [oc][ic][ky][kx]
    int oc = e / 288, ic = (e / 9) % 32, ky = (e / 3) % 3, kx = e % 3;
    wt1[((ky * 3 + kx) * 64 + oc) * 32 + ic] = f2bf(w1[e]);
  } else if (gid < ZTOT + 18432 + 8192) {
    int e = gid - (ZTOT + 18432);
    wt2[e] = f2bf(w2[e]);
  } else if (gid < ZTOT + 18432 + 8192 + 8192) {
    gap[gid - (ZTOT + 18432 + 8192)] = 0.f;
  }
}

// ---------------------------------------------------------------------------
// K1: stem conv 3->32, 3x3 s2 p1, fused BN+ReLU; f32 vector math, writes
// parity-split padded NHWC bf16.
// Lane-paired tile: lanes 2i/2i+1 share a 4-px window and split oc 0-15 /
// 16-31 -> 64 live accs/thread (~4 waves/SIMD vs 2 at 128 accs), while each
// store instruction still fills complete 64-B chunks (adjacent 32-B halves).
// Single-pass structure (R6's 2-px split spilled to scratch; don't).
// Grid (30, 64): block 256 = 120 pairs (4 rows x 30 xg), 240 active.
// ---------------------------------------------------------------------------
__global__ __launch_bounds__(256) void k1_stem(
    const float* __restrict__ x, const float* __restrict__ w,
    const float* __restrict__ alpha, const float* __restrict__ beta,
    US* __restrict__ h1q) {
  __shared__ float wl[C1_ * C0_ * 3 * 4];  // [oc][ic][ky][kx pad4] 1152 f
  int n = blockIdx.y;
  for (int e = threadIdx.x; e < C1_ * 27; e += 256) {
    int oc = e / 27, rem = e % 27;
    int ic = rem / 9, ky = (rem / 3) % 3, kx = rem % 3;
    wl[((oc * C0_ + ic) * 3 + ky) * 4 + kx] = w[e];
  }
  __syncthreads();
  int t = threadIdx.x;
  int pt = t >> 1, ocg = t & 1;
  if (pt >= 120) return;
  int xg = pt % 30, r = pt / 30;
  int y = blockIdx.x * 4 + r;          // 30*4 = 120 exact
  int iy0 = 2 * y - 1;
  int xA = 8 * xg;                     // 16B-aligned window start (v[1])
  int x0m = (xg == 0) ? 0 : (xA - 1);  // clamped scalar addr for v[0]
  bool xg0 = (xg == 0);
  int ocb = ocg * 16;                  // this thread's oc base

  int rofs[3]; bool yok[3];
#pragma unroll
  for (int ky = 0; ky < 3; ky++) {
    int iy = iy0 + ky;
    yok[ky] = (iy >= 0);
    rofs[ky] = (iy < 0 ? 0 : iy) * HW_;
  }

  float acc[16][4];
#pragma unroll
  for (int o = 0; o < 16; o++)
#pragma unroll
    for (int j = 0; j < 4; j++) acc[o][j] = 0.f;

  const float* xn = x + (long)n * C0_ * HW_ * HW_;
#pragma unroll
  for (int ic = 0; ic < C0_; ic++) {
    const float* xc = xn + ic * HW_ * HW_;
#pragma unroll
    for (int ky = 0; ky < 3; ky++) {
      const float* row = xc + rofs[ky];
      float  v0 = row[x0m];
      float4 va = *(const float4*)(row + xA);
      float4 vb = *(const float4*)(row + xA + 4);
      bool ym = yok[ky];
      float v[9];
      v[0] = (ym && !xg0) ? v0 : 0.f;
      v[1] = ym ? va.x : 0.f;  v[2] = ym ? va.y : 0.f;
      v[3] = ym ? va.z : 0.f;  v[4] = ym ? va.w : 0.f;
      v[5] = ym ? vb.x : 0.f;  v[6] = ym ? vb.y : 0.f;
      v[7] = ym ? vb.z : 0.f;  v[8] = ym ? vb.w : 0.f;
#pragma unroll
      for (int o = 0; o < 16; o++) {
        float4 wv = *(const float4*)(wl + (((ocb + o) * C0_ + ic) * 3 + ky) * 4);
#pragma unroll
        for (int j = 0; j < 4; j++) {
          acc[o][j] = fmaf(v[2 * j],     wv.x, acc[o][j]);
          acc[o][j] = fmaf(v[2 * j + 1], wv.y, acc[o][j]);
          acc[o][j] = fmaf(v[2 * j + 2], wv.z, acc[o][j]);
        }
      }
    }
  }
  // parity-split store: gx = 4xg+j; j0->p0 m=2xg, j1->p1 m=2xg+1,
  // j2->p0 m=2xg+1, j3->p1 m=2xg+2. Pair lanes fill full 64-B chunks.
  long rowb = ((long)(n * 122 + y + 1)) * H1Q_ROW;
  long adr[4];
  adr[0] = rowb + (long)(2 * xg) * 32;
  adr[1] = rowb + H1Q_PL + (long)(2 * xg + 1) * 32;
  adr[2] = rowb + (long)(2 * xg + 1) * 32;
  adr[3] = rowb + H1Q_PL + (long)(2 * xg + 2) * 32;
#pragma unroll
  for (int j = 0; j < 4; j++) {
#pragma unroll
    for (int g = 0; g < 2; g++) {
      unsigned q[4];
#pragma unroll
      for (int k = 0; k < 4; k++) {
        int o = g * 8 + 2 * k;          // local 0..15
        int og = ocb + o;               // global oc
        float v0 = fmaxf(fmaf(acc[o][j],     alpha[og],     beta[og]),     0.f);
        float v1 = fmaxf(fmaf(acc[o + 1][j], alpha[og + 1], beta[og + 1]), 0.f);
        q[k] = (unsigned)f2bf(v0) | ((unsigned)f2bf(v1) << 16);
      }
      uint4 u; u.x = q[0]; u.y = q[1]; u.z = q[2]; u.w = q[3];
      *(uint4*)(h1q + adr[j] + ocb + g * 8) = u;
    }
  }
}

// ---------------------------------------------------------------------------
// K2: conv 32->64 3x3 s2 via implicit-GEMM MFMA (bf16 in, f32 acc).
// Parity-split h1q: every A-load coalesced (lanes read consecutive 64-B
// chunks; kx parity selects plane). K = 9 taps x 2 MFMA(K=16).
// Epilogue via LDS -> full 128-B pixel stores. Grid (57, 64).
// ---------------------------------------------------------------------------
__global__ __launch_bounds__(256) void k2_mfma(
    const US* __restrict__ h1q, const US* __restrict__ wt1,
    const float* __restrict__ alpha, const float* __restrict__ beta,
    US* __restrict__ h2p) {
  __shared__ US tile[64 * 64];  // [px_local][oc] bf16, 8 KB
  int n = blockIdx.y, tileb = blockIdx.x;
  int t = threadIdx.x, w = t >> 6, l = t & 63;
  int wm = w & 1, wn = w >> 1;
  int pxb = tileb * 64 + wm * 32;
  int lane31 = l & 31, half = l >> 5;
  int p = pxb + lane31; int pc = p < 3600 ? p : 3599;
  int y = pc / 60, xx = pc % 60;
  int oc = wn * 32 + lane31;

  f32x16 acc;
#pragma unroll
  for (int i = 0; i < 16; i++) acc[i] = 0.f;

#pragma unroll
  for (int ky = 0; ky < 3; ky++) {
    const US* a1 = h1q + ((long)(n * 122 + 2 * y + ky)) * H1Q_ROW
                       + (long)xx * 32 + half * 8;      // kx=1: p0, m=xx
    const US* a0 = a1 + H1Q_PL;                         // kx=0: p1, m=xx
    const US* a2 = a1 + H1Q_PL + 32;                    // kx=2: p1, m=xx+1
    const US* aps[3] = {a0, a1, a2};
    const US* wk = wt1 + (ky * 3) * (64 * 32) + oc * 32 + half * 8;
#pragma unroll
    for (int kx = 0; kx < 3; kx++) {
      const US* ap = aps[kx];
      const US* bp = wk + kx * (64 * 32);
#pragma unroll
      for (int c = 0; c < 2; c++) {
        bf16x8 av = *(const bf16x8*)(ap + c * 16);
        bf16x8 bv = *(const bf16x8*)(bp + c * 16);
        acc = __builtin_amdgcn_mfma_f32_32x32x16_bf16(av, bv, acc, 0, 0, 0);
      }
    }
  }
  float al = alpha[oc], be = beta[oc];
#pragma unroll
  for (int r = 0; r < 16; r++) {
    int row = (r & 3) + 8 * (r >> 2) + 4 * half;
    float v = fmaxf(fmaf(acc[r], al, be), 0.f);
    tile[(wm * 32 + row) * 64 + oc] = f2bf(v);
  }
  __syncthreads();
  int e0 = t * 16;
  int pl = e0 >> 6;
  int pp = tileb * 64 + pl;
  if (pp < 3600) {
    uint4 u0 = *(const uint4*)(tile + e0);
    uint4 u1 = *(const uint4*)(tile + e0 + 8);
    US* dst = h2p + (long)n * 3600 * 64 + (long)pp * 64 + (e0 & 63);
    *(uint4*)dst = u0;
    *(uint4*)(dst + 8) = u1;
  }
}

// ---------------------------------------------------------------------------
// K3: pointwise 64->128 + BN + ReLU + GAP via MFMA. Grid (15, 64).
// ---------------------------------------------------------------------------
__global__ __launch_bounds__(256) void k3_mfma(
    const US* __restrict__ h2p, const US* __restrict__ wt2,
    const float* __restrict__ alpha, const float* __restrict__ beta,
    float* __restrict__ gap) {
  int n = blockIdx.y, chunk = blockIdx.x;
  int t = threadIdx.x, w = t >> 6, l = t & 63;
  int lane31 = l & 31, half = l >> 5;
  int oc = w * 32 + lane31;
  float al = alpha[oc], be = beta[oc];
  const US* bbase = wt2 + oc * 64 + half * 8;
  int t0 = chunk * 8, t1 = t0 + 8;
  if (t1 > 113) t1 = 113;
  const US* h2n = h2p + (long)n * 3600 * 64;
  float s = 0.f;
  for (int tile = t0; tile < t1; tile++) {
    int p0 = tile * 32;
    int p = p0 + lane31; int pc = p < 3600 ? p : 3599;
    const US* aptr = h2n + (long)pc * 64 + half * 8;
    f32x16 acc;
#pragma unroll
    for (int i = 0; i < 16; i++) acc[i] = 0.f;
#pragma unroll
    for (int s4 = 0; s4 < 4; s4++) {
      bf16x8 av = *(const bf16x8*)(aptr + s4 * 16);
      bf16x8 bv = *(const bf16x8*)(bbase + s4 * 16);
      acc = __builtin_amdgcn_mfma_f32_32x32x16_bf16(av, bv, acc, 0, 0, 0);
    }
    if (p0 + 31 < 3600) {
#pragma unroll
      for (int r = 0; r < 16; r++) s += fmaxf(fmaf(acc[r], al, be), 0.f);
    } else {
#pragma unroll
      for (int r = 0; r < 16; r++) {
        int row = (r & 3) + 8 * (r >> 2) + 4 * half;
        if (p0 + row < 3600) s += fmaxf(fmaf(acc[r], al, be), 0.f);
      }
    }
  }
  s += __shfl_xor(s, 32);
  if (half == 0) atomicAdd(gap + n * C3_ + oc, s);
}

// ---------------------------------------------------------------------------
// K4: head — gap/3600 @ w_head^T, BN fold + ReLU (f32).
// ---------------------------------------------------------------------------
__global__ __launch_bounds__(256) void k4_head(
    const float* __restrict__ gap, const float* __restrict__ wh,
    const float* __restrict__ alpha, const float* __restrict__ beta,
    float* __restrict__ out) {
  __shared__ float g[C3_];
  int n = blockIdx.y;
  int o = blockIdx.x * 256 + threadIdx.x;
  if (threadIdx.x < C3_)
    g[threadIdx.x] = gap[n * C3_ + threadIdx.x] * (1.f / 3600.f);
  __syncthreads();
  const float* wr = wh + (long)o * C3_;
  float acc = 0.f;
#pragma unroll 8
  for (int c = 0; c < C3_; c += 4) {
    float4 wv = *(const float4*)(wr + c);
    acc = fmaf(wv.x, g[c],     acc);
    acc = fmaf(wv.y, g[c + 1], acc);
    acc = fmaf(wv.z, g[c + 2], acc);
    acc = fmaf(wv.w, g[c + 3], acc);
  }
  out[n * HEAD_ + o] = fmaxf(fmaf(acc, alpha[o], beta[o]), 0.f);
}

// ---------------------------------------------------------------------------
extern "C" void kernel_launch(void* const* d_in, const int* in_sizes, int n_in,
                              void* d_out, int out_size, void* d_ws,
                              size_t ws_size, hipStream_t stream) {
  const float* x      = (const float*)d_in[0];
  const float* w_stem = (const float*)d_in[1];
  const float* a_stem = (const float*)d_in[2];
  const float* b_stem = (const float*)d_in[3];
  const float* w1     = (const float*)d_in[4];
  const float* a1     = (const float*)d_in[5];
  const float* b1     = (const float*)d_in[6];
  const float* w2     = (const float*)d_in[7];
  const float* a2     = (const float*)d_in[8];
  const float* b2     = (const float*)d_in[9];
  const float* wh     = (const float*)d_in[10];
  const float* ah     = (const float*)d_in[11];
  const float* bh     = (const float*)d_in[12];
  float* out = (float*)d_out;

  US* h1q = (US*)d_ws;                                   // 64*122*3968
  US* h2p = h1q + (size_t)N_ * 122 * H1Q_ROW;            // 64*3600*64
  US* wt1 = h2p + (size_t)N_ * 3600 * 64;                // 9*64*32
  US* wt2 = wt1 + 9 * 64 * 32;                           // 128*64
  float* gap = (float*)(wt2 + C3_ * C2_);                // 64*128 f32

  {  // K0 prep: pad-zero (uint4) + weight conversion + gap zero
    int total = ZTOT + 18432 + 8192 + 8192;
    k0_prep<<<(total + 255) / 256, 256, 0, stream>>>(w1, w2, h1q, wt1, wt2,
                                                     gap);
  }
  {  // K1: 30 row-chunks (4 rows) x 64 n, lane-paired 16oc x 4px
    dim3 grid(30, N_);
    k1_stem<<<grid, 256, 0, stream>>>(x, w_stem, a_stem, b_stem, h1q);
  }
  {  // K2
    dim3 grid(57, N_);
    k2_mfma<<<grid, 256, 0, stream>>>(h1q, wt1, a1, b1, h2p);
  }
  {  // K3
    dim3 grid(15, N_);
    k3_mfma<<<grid, 256, 0, stream>>>(h2p, wt2, a2, b2, gap);
  }
  {  // K4
    dim3 grid(HEAD_ / 256, N_);
    k4_head<<<grid, 256, 0, stream>>>(gap, wh, ah, bh, out);
  }
}

// Round 10
// 210.050 us; speedup vs baseline: 1.1071x; 1.1071x over previous
//
#include <hip/hip_runtime.h>

#define N_    64
#define HW_   240
#define H1_   120
#define H2_   60
#define C0_   3
#define C1_   32
#define C2_   64
#define C3_   128
#define HEAD_ 1280

typedef unsigned short US;
typedef short bf16x8 __attribute__((ext_vector_type(8)));
typedef float f32x16 __attribute__((ext_vector_type(16)));

__device__ __forceinline__ US f2bf(float f) {
  union { float f; unsigned u; } v; v.f = f;
  unsigned r = v.u + 0x7FFF + ((v.u >> 16) & 1);  // RNE
  return (US)(r >> 16);
}

// h1q parity-split padded NHWC bf16: [n][row 122][parity 2][xh 62][32ch].
// h1 pixel (gy,gx): row = gy+1; gx even=2m -> plane0[m]; gx odd=2m-1 -> plane1[m].
// Row stride 3968 elems; plane stride 1984.
#define H1Q_ROW 3968
#define H1Q_PL  1984

// ---------------------------------------------------------------------------
// K0: prep — zero h1q cells k2 reads but k1 doesn't write (uint4);
// w1 -> wt1 [ky][kx][oc][ic] bf16; w2 -> wt2 [oc][ic] bf16; zero gap.
// ---------------------------------------------------------------------------
#define ZCHN   368                 // zero-chunks per n (124+124+120)
#define ZTOT   (64 * ZCHN * 4)     // uint4 stores total = 94208
__global__ __launch_bounds__(256) void k0_prep(
    const float* __restrict__ w1, const float* __restrict__ w2,
    US* __restrict__ h1q, US* __restrict__ wt1, US* __restrict__ wt2,
    float* __restrict__ gap) {
  int gid = blockIdx.x * 256 + threadIdx.x;
  if (gid < ZTOT) {
    int c = gid >> 2, q = gid & 3;
    int n = c / ZCHN, cc = c % ZCHN;
    long off; int y;
    if (cc < 124)      { y = 0;   off = (long)cc * 32; }
    else if (cc < 248) { y = 121; off = (long)(cc - 124) * 32; }
    else               { y = cc - 247; off = H1Q_PL; }   // p1 m=0, rows 1..120
    uint4 z; z.x = z.y = z.z = z.w = 0u;
    *(uint4*)(h1q + ((long)(n * 122 + y)) * H1Q_ROW + off + q * 8) = z;
  } else if (gid < ZTOT + 18432) {
    int e = gid - ZTOT;                       // w1 flat [oc][ic][ky][kx]
    int oc = e / 288, ic = (e / 9) % 32, ky = (e / 3) % 3, kx = e % 3;
    wt1[((ky * 3 + kx) * 64 + oc) * 32 + ic] = f2bf(w1[e]);
  } else if (gid < ZTOT + 18432 + 8192) {
    int e = gid - (ZTOT + 18432);
    wt2[e] = f2bf(w2[e]);
  } else if (gid < ZTOT + 18432 + 8192 + 8192) {
    gap[gid - (ZTOT + 18432 + 8192)] = 0.f;
  }
}

// ---------------------------------------------------------------------------
// K1: stem conv 3->32, 3x3 s2 p1, fused BN+ReLU; f32 vector math, writes
// parity-split padded NHWC bf16. Thread: 32 oc x 4 px (128 accs; compiler
// parks them in unified AGPR file at VGPR~84 — 66 us measured). LOCKED
// CONFIG: R6 2-px split -> scratch spill 1.4ms; R9 lane-pairing -> 343x LDS
// bank conflicts (paired wl addrs alias bank 0). Do not restructure.
// Grid (15, 64), 240/256 threads active.
// ---------------------------------------------------------------------------
__global__ __launch_bounds__(256) void k1_stem(
    const float* __restrict__ x, const float* __restrict__ w,
    const float* __restrict__ alpha, const float* __restrict__ beta,
    US* __restrict__ h1q) {
  __shared__ float wl[C1_ * C0_ * 3 * 4];  // [oc][ic][ky][kx pad4] 1152 f
  int n = blockIdx.y;
  for (int e = threadIdx.x; e < C1_ * 27; e += 256) {
    int oc = e / 27, rem = e % 27;
    int ic = rem / 9, ky = (rem / 3) % 3, kx = rem % 3;
    wl[((oc * C0_ + ic) * 3 + ky) * 4 + kx] = w[e];
  }
  __syncthreads();
  int t = threadIdx.x;
  if (t >= 240) return;
  int xg = t % 30, r = t / 30;
  int y = blockIdx.x * 8 + r;          // 15*8 = 120 exact
  int iy0 = 2 * y - 1;
  int xA = 8 * xg;                     // 16B-aligned window start (v[1])
  int x0m = (xg == 0) ? 0 : (xA - 1);  // clamped scalar addr for v[0]
  bool xg0 = (xg == 0);

  int rofs[3]; bool yok[3];
#pragma unroll
  for (int ky = 0; ky < 3; ky++) {
    int iy = iy0 + ky;
    yok[ky] = (iy >= 0);
    rofs[ky] = (iy < 0 ? 0 : iy) * HW_;
  }

  float acc[C1_][4];
#pragma unroll
  for (int o = 0; o < C1_; o++)
#pragma unroll
    for (int j = 0; j < 4; j++) acc[o][j] = 0.f;

  const float* xn = x + (long)n * C0_ * HW_ * HW_;
#pragma unroll
  for (int ic = 0; ic < C0_; ic++) {
    const float* xc = xn + ic * HW_ * HW_;
#pragma unroll
    for (int ky = 0; ky < 3; ky++) {
      const float* row = xc + rofs[ky];
      float  v0 = row[x0m];
      float4 va = *(const float4*)(row + xA);
      float4 vb = *(const float4*)(row + xA + 4);
      bool ym = yok[ky];
      float v[9];
      v[0] = (ym && !xg0) ? v0 : 0.f;
      v[1] = ym ? va.x : 0.f;  v[2] = ym ? va.y : 0.f;
      v[3] = ym ? va.z : 0.f;  v[4] = ym ? va.w : 0.f;
      v[5] = ym ? vb.x : 0.f;  v[6] = ym ? vb.y : 0.f;
      v[7] = ym ? vb.z : 0.f;  v[8] = ym ? vb.w : 0.f;
#pragma unroll
      for (int oc = 0; oc < C1_; oc++) {
        float4 wv = *(const float4*)(wl + ((oc * C0_ + ic) * 3 + ky) * 4);
#pragma unroll
        for (int j = 0; j < 4; j++) {
          acc[oc][j] = fmaf(v[2 * j],     wv.x, acc[oc][j]);
          acc[oc][j] = fmaf(v[2 * j + 1], wv.y, acc[oc][j]);
          acc[oc][j] = fmaf(v[2 * j + 2], wv.z, acc[oc][j]);
        }
      }
    }
  }
  // parity-split store: gx = 4xg+j; j0->p0 m=2xg, j1->p1 m=2xg+1,
  // j2->p0 m=2xg+1, j3->p1 m=2xg+2. Full 64-B chunks.
  long rowb = ((long)(n * 122 + y + 1)) * H1Q_ROW;
  long adr[4];
  adr[0] = rowb + (long)(2 * xg) * 32;
  adr[1] = rowb + H1Q_PL + (long)(2 * xg + 1) * 32;
  adr[2] = rowb + (long)(2 * xg + 1) * 32;
  adr[3] = rowb + H1Q_PL + (long)(2 * xg + 2) * 32;
#pragma unroll
  for (int j = 0; j < 4; j++) {
#pragma unroll
    for (int g = 0; g < 4; g++) {
      unsigned q[4];
#pragma unroll
      for (int k = 0; k < 4; k++) {
        int o = g * 8 + 2 * k;
        float v0 = fmaxf(fmaf(acc[o][j],     alpha[o],     beta[o]),     0.f);
        float v1 = fmaxf(fmaf(acc[o + 1][j], alpha[o + 1], beta[o + 1]), 0.f);
        q[k] = (unsigned)f2bf(v0) | ((unsigned)f2bf(v1) << 16);
      }
      uint4 u; u.x = q[0]; u.y = q[1]; u.z = q[2]; u.w = q[3];
      *(uint4*)(h1q + adr[j] + g * 8) = u;
    }
  }
}

// ---------------------------------------------------------------------------
// K2: FUSED conv2 (32->64 3x3 s2, implicit-GEMM MFMA) + pointwise conv3
// (64->128) + BN/ReLU + GAP. h2 is never written to global.
// Stage A: 64px x 64oc tile, 4 waves (2x2); A coalesced from parity-split
//   h1q; 18 MFMA/wave; BN+ReLU; bf16 tile -> LDS [64px][stride 72].
// Stage B: GEMM tile[64px][64k] x wt2[64k][128oc2]; wave w: px-half (w&1),
//   oc2-half (w>>1); 8 MFMA/wave; BN+ReLU; masked row-sum; shfl_xor(32);
//   one atomicAdd per oc2 per wave. Grid (57, 64).
// ---------------------------------------------------------------------------
#define TS 72   // LDS tile row stride (US); 144 B = 16B-aligned, non-pow2
__global__ __launch_bounds__(256) void k2_fused(
    const US* __restrict__ h1q, const US* __restrict__ wt1,
    const US* __restrict__ wt2,
    const float* __restrict__ a1, const float* __restrict__ b1,
    const float* __restrict__ a2, const float* __restrict__ b2,
    float* __restrict__ gap) {
  __shared__ US tile[64 * TS];  // 9216 B
  int n = blockIdx.y, tileb = blockIdx.x;
  int t = threadIdx.x, w = t >> 6, l = t & 63;
  int wm = w & 1, wn = w >> 1;
  int pxb = tileb * 64 + wm * 32;
  int lane31 = l & 31, half = l >> 5;
  int p = pxb + lane31; int pc = p < 3600 ? p : 3599;
  int y = pc / 60, xx = pc % 60;
  int oc = wn * 32 + lane31;

  f32x16 acc;
#pragma unroll
  for (int i = 0; i < 16; i++) acc[i] = 0.f;

#pragma unroll
  for (int ky = 0; ky < 3; ky++) {
    const US* a1p = h1q + ((long)(n * 122 + 2 * y + ky)) * H1Q_ROW
                        + (long)xx * 32 + half * 8;     // kx=1: p0, m=xx
    const US* a0p = a1p + H1Q_PL;                       // kx=0: p1, m=xx
    const US* a2p = a1p + H1Q_PL + 32;                  // kx=2: p1, m=xx+1
    const US* aps[3] = {a0p, a1p, a2p};
    const US* wk = wt1 + (ky * 3) * (64 * 32) + oc * 32 + half * 8;
#pragma unroll
    for (int kx = 0; kx < 3; kx++) {
      const US* ap = aps[kx];
      const US* bp = wk + kx * (64 * 32);
#pragma unroll
      for (int c = 0; c < 2; c++) {
        bf16x8 av = *(const bf16x8*)(ap + c * 16);
        bf16x8 bv = *(const bf16x8*)(bp + c * 16);
        acc = __builtin_amdgcn_mfma_f32_32x32x16_bf16(av, bv, acc, 0, 0, 0);
      }
    }
  }
  {  // h2 tile -> LDS (bf16, BN+ReLU applied)
    float al = a1[oc], be = b1[oc];
#pragma unroll
    for (int r = 0; r < 16; r++) {
      int row = (r & 3) + 8 * (r >> 2) + 4 * half;
      float v = fmaxf(fmaf(acc[r], al, be), 0.f);
      tile[(wm * 32 + row) * TS + oc] = f2bf(v);
    }
  }
  __syncthreads();

  // Stage B: pointwise 64->128 + BN + ReLU + GAP partial sums
  int wm2 = w & 1, wn2 = w >> 1;
  int base_px = tileb * 64 + wm2 * 32;
  const US* abase2 = tile + (wm2 * 32 + lane31) * TS + half * 8;
#pragma unroll
  for (int nt = 0; nt < 2; nt++) {
    int oc2 = wn2 * 64 + nt * 32 + lane31;
    const US* bb = wt2 + oc2 * 64 + half * 8;
    f32x16 acc2;
#pragma unroll
    for (int i = 0; i < 16; i++) acc2[i] = 0.f;
#pragma unroll
    for (int c = 0; c < 4; c++) {
      bf16x8 av = *(const bf16x8*)(abase2 + c * 16);
      bf16x8 bv = *(const bf16x8*)(bb + c * 16);
      acc2 = __builtin_amdgcn_mfma_f32_32x32x16_bf16(av, bv, acc2, 0, 0, 0);
    }
    float al2 = a2[oc2], be2 = b2[oc2];
    float s = 0.f;
    if (base_px + 31 < 3600) {
#pragma unroll
      for (int r = 0; r < 16; r++) s += fmaxf(fmaf(acc2[r], al2, be2), 0.f);
    } else {
#pragma unroll
      for (int r = 0; r < 16; r++) {
        int row = (r & 3) + 8 * (r >> 2) + 4 * half;
        if (base_px + row < 3600) s += fmaxf(fmaf(acc2[r], al2, be2), 0.f);
      }
    }
    s += __shfl_xor(s, 32);
    if (half == 0) atomicAdd(gap + n * C3_ + oc2, s);
  }
}

// ---------------------------------------------------------------------------
// K4: head — gap/3600 @ w_head^T, BN fold + ReLU (f32).
// ---------------------------------------------------------------------------
__global__ __launch_bounds__(256) void k4_head(
    const float* __restrict__ gap, const float* __restrict__ wh,
    const float* __restrict__ alpha, const float* __restrict__ beta,
    float* __restrict__ out) {
  __shared__ float g[C3_];
  int n = blockIdx.y;
  int o = blockIdx.x * 256 + threadIdx.x;
  if (threadIdx.x < C3_)
    g[threadIdx.x] = gap[n * C3_ + threadIdx.x] * (1.f / 3600.f);
  __syncthreads();
  const float* wr = wh + (long)o * C3_;
  float acc = 0.f;
#pragma unroll 8
  for (int c = 0; c < C3_; c += 4) {
    float4 wv = *(const float4*)(wr + c);
    acc = fmaf(wv.x, g[c],     acc);
    acc = fmaf(wv.y, g[c + 1], acc);
    acc = fmaf(wv.z, g[c + 2], acc);
    acc = fmaf(wv.w, g[c + 3], acc);
  }
  out[n * HEAD_ + o] = fmaxf(fmaf(acc, alpha[o], beta[o]), 0.f);
}

// ---------------------------------------------------------------------------
extern "C" void kernel_launch(void* const* d_in, const int* in_sizes, int n_in,
                              void* d_out, int out_size, void* d_ws,
                              size_t ws_size, hipStream_t stream) {
  const float* x      = (const float*)d_in[0];
  const float* w_stem = (const float*)d_in[1];
  const float* a_stem = (const float*)d_in[2];
  const float* b_stem = (const float*)d_in[3];
  const float* w1     = (const float*)d_in[4];
  const float* a1     = (const float*)d_in[5];
  const float* b1     = (const float*)d_in[6];
  const float* w2     = (const float*)d_in[7];
  const float* a2     = (const float*)d_in[8];
  const float* b2     = (const float*)d_in[9];
  const float* wh     = (const float*)d_in[10];
  const float* ah     = (const float*)d_in[11];
  const float* bh     = (const float*)d_in[12];
  float* out = (float*)d_out;

  US* h1q = (US*)d_ws;                                   // 64*122*3968
  US* wt1 = h1q + (size_t)N_ * 122 * H1Q_ROW;            // 9*64*32
  US* wt2 = wt1 + 9 * 64 * 32;                           // 128*64
  float* gap = (float*)(wt2 + C3_ * C2_);                // 64*128 f32

  {  // K0 prep: pad-zero (uint4) + weight conversion + gap zero
    int total = ZTOT + 18432 + 8192 + 8192;
    k0_prep<<<(total + 255) / 256, 256, 0, stream>>>(w1, w2, h1q, wt1, wt2,
                                                     gap);
  }
  {  // K1: 15 row-chunks x 64 n
    dim3 grid(15, N_);
    k1_stem<<<grid, 256, 0, stream>>>(x, w_stem, a_stem, b_stem, h1q);
  }
  {  // K2 fused conv2+conv3+GAP
    dim3 grid(57, N_);
    k2_fused<<<grid, 256, 0, stream>>>(h1q, wt1, wt2, a1, b1, a2, b2, gap);
  }
  {  // K4
    dim3 grid(HEAD_ / 256, N_);
    k4_head<<<grid, 256, 0, stream>>>(gap, wh, ah, bh, out);
  }
}

// Round 11
// 202.988 us; speedup vs baseline: 1.1456x; 1.0348x over previous
//
#include <hip/hip_runtime.h>

#define N_    64
#define HW_   240
#define H1_   120
#define H2_   60
#define C0_   3
#define C1_   32
#define C2_   64
#define C3_   128
#define HEAD_ 1280

typedef unsigned short US;
typedef short bf16x8 __attribute__((ext_vector_type(8)));
typedef float f32x16 __attribute__((ext_vector_type(16)));

__device__ __forceinline__ US f2bf(float f) {
  union { float f; unsigned u; } v; v.f = f;
  unsigned r = v.u + 0x7FFF + ((v.u >> 16) & 1);  // RNE
  return (US)(r >> 16);
}

// h1q parity-split padded NHWC bf16: [n][row 122][parity 2][xh 62][32ch].
// h1 pixel (gy,gx): row = gy+1; gx even=2m -> plane0[m]; gx odd=2m-1 -> plane1[m].
// Row stride 3968 elems; plane stride 1984.
#define H1Q_ROW 3968
#define H1Q_PL  1984

// ---------------------------------------------------------------------------
// K0: prep — zero h1q cells k2 reads but k1 doesn't write (uint4);
// w1 -> wt1 [ky][kx][oc][ic] bf16; w2 -> wt2 [oc][ic] bf16; zero gap.
// ---------------------------------------------------------------------------
#define ZCHN   368                 // zero-chunks per n (124+124+120)
#define ZTOT   (64 * ZCHN * 4)     // uint4 stores total = 94208
__global__ __launch_bounds__(256) void k0_prep(
    const float* __restrict__ w1, const float* __restrict__ w2,
    US* __restrict__ h1q, US* __restrict__ wt1, US* __restrict__ wt2,
    float* __restrict__ gap) {
  int gid = blockIdx.x * 256 + threadIdx.x;
  if (gid < ZTOT) {
    int c = gid >> 2, q = gid & 3;
    int n = c / ZCHN, cc = c % ZCHN;
    long off; int y;
    if (cc < 124)      { y = 0;   off = (long)cc * 32; }
    else if (cc < 248) { y = 121; off = (long)(cc - 124) * 32; }
    else               { y = cc - 247; off = H1Q_PL; }   // p1 m=0, rows 1..120
    uint4 z; z.x = z.y = z.z = z.w = 0u;
    *(uint4*)(h1q + ((long)(n * 122 + y)) * H1Q_ROW + off + q * 8) = z;
  } else if (gid < ZTOT + 18432) {
    int e = gid - ZTOT;                       // w1 flat [oc][ic][ky][kx]
    int oc = e / 288, ic = (e / 9) % 32, ky = (e / 3) % 3, kx = e % 3;
    wt1[((ky * 3 + kx) * 64 + oc) * 32 + ic] = f2bf(w1[e]);
  } else if (gid < ZTOT + 18432 + 8192) {
    int e = gid - (ZTOT + 18432);
    wt2[e] = f2bf(w2[e]);
  } else if (gid < ZTOT + 18432 + 8192 + 8192) {
    gap[gid - (ZTOT + 18432 + 8192)] = 0.f;
  }
}

// ---------------------------------------------------------------------------
// K1: stem conv 3->32, 3x3 s2 p1, fused BN+ReLU; f32 vector math, writes
// parity-split padded NHWC bf16. Thread: 32 oc x 4 px (128 accs; compiler
// parks them in unified AGPR file at VGPR~84 — 66 us measured). LOCKED
// CONFIG: R6 2-px split -> scratch spill 1.4ms; R9 lane-pairing -> 343x LDS
// bank conflicts (paired wl addrs alias bank 0). Do not restructure.
// Grid (15, 64), 240/256 threads active.
// ---------------------------------------------------------------------------
__global__ __launch_bounds__(256) void k1_stem(
    const float* __restrict__ x, const float* __restrict__ w,
    const float* __restrict__ alpha, const float* __restrict__ beta,
    US* __restrict__ h1q) {
  __shared__ float wl[C1_ * C0_ * 3 * 4];  // [oc][ic][ky][kx pad4] 1152 f
  int n = blockIdx.y;
  for (int e = threadIdx.x; e < C1_ * 27; e += 256) {
    int oc = e / 27, rem = e % 27;
    int ic = rem / 9, ky = (rem / 3) % 3, kx = rem % 3;
    wl[((oc * C0_ + ic) * 3 + ky) * 4 + kx] = w[e];
  }
  __syncthreads();
  int t = threadIdx.x;
  if (t >= 240) return;
  int xg = t % 30, r = t / 30;
  int y = blockIdx.x * 8 + r;          // 15*8 = 120 exact
  int iy0 = 2 * y - 1;
  int xA = 8 * xg;                     // 16B-aligned window start (v[1])
  int x0m = (xg == 0) ? 0 : (xA - 1);  // clamped scalar addr for v[0]
  bool xg0 = (xg == 0);

  int rofs[3]; bool yok[3];
#pragma unroll
  for (int ky = 0; ky < 3; ky++) {
    int iy = iy0 + ky;
    yok[ky] = (iy >= 0);
    rofs[ky] = (iy < 0 ? 0 : iy) * HW_;
  }

  float acc[C1_][4];
#pragma unroll
  for (int o = 0; o < C1_; o++)
#pragma unroll
    for (int j = 0; j < 4; j++) acc[o][j] = 0.f;

  const float* xn = x + (long)n * C0_ * HW_ * HW_;
#pragma unroll
  for (int ic = 0; ic < C0_; ic++) {
    const float* xc = xn + ic * HW_ * HW_;
#pragma unroll
    for (int ky = 0; ky < 3; ky++) {
      const float* row = xc + rofs[ky];
      float  v0 = row[x0m];
      float4 va = *(const float4*)(row + xA);
      float4 vb = *(const float4*)(row + xA + 4);
      bool ym = yok[ky];
      float v[9];
      v[0] = (ym && !xg0) ? v0 : 0.f;
      v[1] = ym ? va.x : 0.f;  v[2] = ym ? va.y : 0.f;
      v[3] = ym ? va.z : 0.f;  v[4] = ym ? va.w : 0.f;
      v[5] = ym ? vb.x : 0.f;  v[6] = ym ? vb.y : 0.f;
      v[7] = ym ? vb.z : 0.f;  v[8] = ym ? vb.w : 0.f;
#pragma unroll
      for (int oc = 0; oc < C1_; oc++) {
        float4 wv = *(const float4*)(wl + ((oc * C0_ + ic) * 3 + ky) * 4);
#pragma unroll
        for (int j = 0; j < 4; j++) {
          acc[oc][j] = fmaf(v[2 * j],     wv.x, acc[oc][j]);
          acc[oc][j] = fmaf(v[2 * j + 1], wv.y, acc[oc][j]);
          acc[oc][j] = fmaf(v[2 * j + 2], wv.z, acc[oc][j]);
        }
      }
    }
  }
  // parity-split store: gx = 4xg+j; j0->p0 m=2xg, j1->p1 m=2xg+1,
  // j2->p0 m=2xg+1, j3->p1 m=2xg+2. Full 64-B chunks.
  long rowb = ((long)(n * 122 + y + 1)) * H1Q_ROW;
  long adr[4];
  adr[0] = rowb + (long)(2 * xg) * 32;
  adr[1] = rowb + H1Q_PL + (long)(2 * xg + 1) * 32;
  adr[2] = rowb + (long)(2 * xg + 1) * 32;
  adr[3] = rowb + H1Q_PL + (long)(2 * xg + 2) * 32;
#pragma unroll
  for (int j = 0; j < 4; j++) {
#pragma unroll
    for (int g = 0; g < 4; g++) {
      unsigned q[4];
#pragma unroll
      for (int k = 0; k < 4; k++) {
        int o = g * 8 + 2 * k;
        float v0 = fmaxf(fmaf(acc[o][j],     alpha[o],     beta[o]),     0.f);
        float v1 = fmaxf(fmaf(acc[o + 1][j], alpha[o + 1], beta[o + 1]), 0.f);
        q[k] = (unsigned)f2bf(v0) | ((unsigned)f2bf(v1) << 16);
      }
      uint4 u; u.x = q[0]; u.y = q[1]; u.z = q[2]; u.w = q[3];
      *(uint4*)(h1q + adr[j] + g * 8) = u;
    }
  }
}

// ---------------------------------------------------------------------------
// K2: FUSED conv2 + conv3 + BN/ReLU + GAP, ILP-widened.
// Block tile 128 px x 64 oc1, 4 waves. Each wave: TWO independent 32-px
// Stage-A MFMA chains (36 MFMA, B-frags shared) -> LDS tile [128][TS].
// Stage B: wave w owns px-quarter w, all 128 oc2 in 4 independent nt chains;
// A-frags loaded from LDS ONCE and reused across nt (4 ds_read_b128/lane).
// Grid (29, 64); px tile 28 masked beyond 3600.
// ---------------------------------------------------------------------------
#define TS 72   // LDS tile row stride (US); 144 B, 16B-aligned, non-pow2
__global__ __launch_bounds__(256) void k2_fused(
    const US* __restrict__ h1q, const US* __restrict__ wt1,
    const US* __restrict__ wt2,
    const float* __restrict__ a1, const float* __restrict__ b1,
    const float* __restrict__ a2, const float* __restrict__ b2,
    float* __restrict__ gap) {
  __shared__ US tile[128 * TS];  // 18432 B
  int n = blockIdx.y, tileb = blockIdx.x;
  int t = threadIdx.x, w = t >> 6, l = t & 63;
  int wm = w & 1, wn = w >> 1;
  int lane31 = l & 31, half = l >> 5;
  int oc = wn * 32 + lane31;

  // two px chains for this wave
  int pxb0 = tileb * 128 + wm * 64;
  int pxb1 = pxb0 + 32;
  int p0 = pxb0 + lane31; int pc0 = p0 < 3600 ? p0 : 3599;
  int p1 = pxb1 + lane31; int pc1 = p1 < 3600 ? p1 : 3599;
  int y0 = pc0 / 60, xx0 = pc0 % 60;
  int y1 = pc1 / 60, xx1 = pc1 % 60;

  f32x16 accA, accB;
#pragma unroll
  for (int i = 0; i < 16; i++) { accA[i] = 0.f; accB[i] = 0.f; }

#pragma unroll
  for (int ky = 0; ky < 3; ky++) {
    const US* c0a1 = h1q + ((long)(n * 122 + 2 * y0 + ky)) * H1Q_ROW
                         + (long)xx0 * 32 + half * 8;   // kx=1: p0 plane
    const US* c1a1 = h1q + ((long)(n * 122 + 2 * y1 + ky)) * H1Q_ROW
                         + (long)xx1 * 32 + half * 8;
    const US* wk = wt1 + (ky * 3) * (64 * 32) + oc * 32 + half * 8;
#pragma unroll
    for (int kx = 0; kx < 3; kx++) {
      long aoff = (kx == 1) ? 0 : (kx == 0 ? H1Q_PL : (H1Q_PL + 32));
      const US* bp = wk + kx * (64 * 32);
#pragma unroll
      for (int c = 0; c < 2; c++) {
        bf16x8 bv  = *(const bf16x8*)(bp + c * 16);
        bf16x8 av0 = *(const bf16x8*)(c0a1 + aoff + c * 16);
        bf16x8 av1 = *(const bf16x8*)(c1a1 + aoff + c * 16);
        accA = __builtin_amdgcn_mfma_f32_32x32x16_bf16(av0, bv, accA, 0, 0, 0);
        accB = __builtin_amdgcn_mfma_f32_32x32x16_bf16(av1, bv, accB, 0, 0, 0);
      }
    }
  }
  {  // h2 tiles -> LDS (bf16, BN+ReLU applied)
    float al = a1[oc], be = b1[oc];
#pragma unroll
    for (int r = 0; r < 16; r++) {
      int row = (r & 3) + 8 * (r >> 2) + 4 * half;
      float vA = fmaxf(fmaf(accA[r], al, be), 0.f);
      float vB = fmaxf(fmaf(accB[r], al, be), 0.f);
      tile[(wm * 64 + row) * TS + oc] = f2bf(vA);
      tile[(wm * 64 + 32 + row) * TS + oc] = f2bf(vB);
    }
  }
  __syncthreads();

  // Stage B: px-quarter w x 128 oc2; A-frags loaded once, reused over nt
  int base_px = tileb * 128 + w * 32;
  const US* abase2 = tile + (w * 32 + lane31) * TS + half * 8;
  bf16x8 af[4];
#pragma unroll
  for (int c = 0; c < 4; c++) af[c] = *(const bf16x8*)(abase2 + c * 16);

#pragma unroll
  for (int nt = 0; nt < 4; nt++) {
    int oc2 = nt * 32 + lane31;
    const US* bb = wt2 + oc2 * 64 + half * 8;
    f32x16 acc2;
#pragma unroll
    for (int i = 0; i < 16; i++) acc2[i] = 0.f;
#pragma unroll
    for (int c = 0; c < 4; c++) {
      bf16x8 bv = *(const bf16x8*)(bb + c * 16);
      acc2 = __builtin_amdgcn_mfma_f32_32x32x16_bf16(af[c], bv, acc2, 0, 0, 0);
    }
    float al2 = a2[oc2], be2 = b2[oc2];
    float s = 0.f;
    if (base_px + 31 < 3600) {
#pragma unroll
      for (int r = 0; r < 16; r++) s += fmaxf(fmaf(acc2[r], al2, be2), 0.f);
    } else {
#pragma unroll
      for (int r = 0; r < 16; r++) {
        int row = (r & 3) + 8 * (r >> 2) + 4 * half;
        if (base_px + row < 3600) s += fmaxf(fmaf(acc2[r], al2, be2), 0.f);
      }
    }
    s += __shfl_xor(s, 32);
    if (half == 0) atomicAdd(gap + n * C3_ + oc2, s);
  }
}

// ---------------------------------------------------------------------------
// K4: head — gap/3600 @ w_head^T, BN fold + ReLU (f32).
// ---------------------------------------------------------------------------
__global__ __launch_bounds__(256) void k4_head(
    const float* __restrict__ gap, const float* __restrict__ wh,
    const float* __restrict__ alpha, const float* __restrict__ beta,
    float* __restrict__ out) {
  __shared__ float g[C3_];
  int n = blockIdx.y;
  int o = blockIdx.x * 256 + threadIdx.x;
  if (threadIdx.x < C3_)
    g[threadIdx.x] = gap[n * C3_ + threadIdx.x] * (1.f / 3600.f);
  __syncthreads();
  const float* wr = wh + (long)o * C3_;
  float acc = 0.f;
#pragma unroll 8
  for (int c = 0; c < C3_; c += 4) {
    float4 wv = *(const float4*)(wr + c);
    acc = fmaf(wv.x, g[c],     acc);
    acc = fmaf(wv.y, g[c + 1], acc);
    acc = fmaf(wv.z, g[c + 2], acc);
    acc = fmaf(wv.w, g[c + 3], acc);
  }
  out[n * HEAD_ + o] = fmaxf(fmaf(acc, alpha[o], beta[o]), 0.f);
}

// ---------------------------------------------------------------------------
extern "C" void kernel_launch(void* const* d_in, const int* in_sizes, int n_in,
                              void* d_out, int out_size, void* d_ws,
                              size_t ws_size, hipStream_t stream) {
  const float* x      = (const float*)d_in[0];
  const float* w_stem = (const float*)d_in[1];
  const float* a_stem = (const float*)d_in[2];
  const float* b_stem = (const float*)d_in[3];
  const float* w1     = (const float*)d_in[4];
  const float* a1     = (const float*)d_in[5];
  const float* b1     = (const float*)d_in[6];
  const float* w2     = (const float*)d_in[7];
  const float* a2     = (const float*)d_in[8];
  const float* b2     = (const float*)d_in[9];
  const float* wh     = (const float*)d_in[10];
  const float* ah     = (const float*)d_in[11];
  const float* bh     = (const float*)d_in[12];
  float* out = (float*)d_out;

  US* h1q = (US*)d_ws;                                   // 64*122*3968
  US* wt1 = h1q + (size_t)N_ * 122 * H1Q_ROW;            // 9*64*32
  US* wt2 = wt1 + 9 * 64 * 32;                           // 128*64
  float* gap = (float*)(wt2 + C3_ * C2_);                // 64*128 f32

  {  // K0 prep: pad-zero (uint4) + weight conversion + gap zero
    int total = ZTOT + 18432 + 8192 + 8192;
    k0_prep<<<(total + 255) / 256, 256, 0, stream>>>(w1, w2, h1q, wt1, wt2,
                                                     gap);
  }
  {  // K1: 15 row-chunks x 64 n
    dim3 grid(15, N_);
    k1_stem<<<grid, 256, 0, stream>>>(x, w_stem, a_stem, b_stem, h1q);
  }
  {  // K2 fused conv2+conv3+GAP, 128-px tiles
    dim3 grid(29, N_);
    k2_fused<<<grid, 256, 0, stream>>>(h1q, wt1, wt2, a1, b1, a2, b2, gap);
  }
  {  // K4
    dim3 grid(HEAD_ / 256, N_);
    k4_head<<<grid, 256, 0, stream>>>(gap, wh, ah, bh, out);
  }
}

// Round 12
// 183.000 us; speedup vs baseline: 1.2708x; 1.1092x over previous
//
#include <hip/hip_runtime.h>

#define N_    64
#define HW_   240
#define H1_   120
#define H2_   60
#define C0_   3
#define C1_   32
#define C2_   64
#define C3_   128
#define HEAD_ 1280

typedef unsigned short US;
typedef short bf16x8 __attribute__((ext_vector_type(8)));
typedef float f32x16 __attribute__((ext_vector_type(16)));

__device__ __forceinline__ US f2bf(float f) {
  union { float f; unsigned u; } v; v.f = f;
  unsigned r = v.u + 0x7FFF + ((v.u >> 16) & 1);  // RNE
  return (US)(r >> 16);
}

// h1q parity-split padded NHWC bf16: [n][row 122][parity 2][xh 62][32ch].
// h1 pixel (gy,gx): row = gy+1; gx even=2m -> plane0[m]; gx odd=2m-1 -> plane1[m].
#define H1Q_ROW 3968
#define H1Q_PL  1984

// ---------------------------------------------------------------------------
// K0: prep — zero h1q pad cells (uint4); w1 -> wt1 [ky][kx][oc][ic] bf16;
// w2 -> wt2 [oc][ic] bf16; w_stem -> wt0 [oc][k32] bf16 (k=ic*9+ky*3+kx,
// k>=27 zero); zero gap.
// ---------------------------------------------------------------------------
#define ZCHN   368                 // zero-chunks per n (124+124+120)
#define ZTOT   (64 * ZCHN * 4)     // 94208
__global__ __launch_bounds__(256) void k0_prep(
    const float* __restrict__ w1, const float* __restrict__ w2,
    const float* __restrict__ w0,
    US* __restrict__ h1q, US* __restrict__ wt1, US* __restrict__ wt2,
    US* __restrict__ wt0, float* __restrict__ gap) {
  int gid = blockIdx.x * 256 + threadIdx.x;
  if (gid < ZTOT) {
    int c = gid >> 2, q = gid & 3;
    int n = c / ZCHN, cc = c % ZCHN;
    long off; int y;
    if (cc < 124)      { y = 0;   off = (long)cc * 32; }
    else if (cc < 248) { y = 121; off = (long)(cc - 124) * 32; }
    else               { y = cc - 247; off = H1Q_PL; }   // p1 m=0, rows 1..120
    uint4 z; z.x = z.y = z.z = z.w = 0u;
    *(uint4*)(h1q + ((long)(n * 122 + y)) * H1Q_ROW + off + q * 8) = z;
  } else if (gid < ZTOT + 18432) {
    int e = gid - ZTOT;                       // w1 flat [oc][ic][ky][kx]
    int oc = e / 288, ic = (e / 9) % 32, ky = (e / 3) % 3, kx = e % 3;
    wt1[((ky * 3 + kx) * 64 + oc) * 32 + ic] = f2bf(w1[e]);
  } else if (gid < ZTOT + 18432 + 8192) {
    int e = gid - (ZTOT + 18432);
    wt2[e] = f2bf(w2[e]);
  } else if (gid < ZTOT + 18432 + 8192 + 1024) {
    int e = gid - (ZTOT + 18432 + 8192);      // e = oc*32 + k
    int oc = e >> 5, k = e & 31;
    wt0[e] = (k < 27) ? f2bf(w0[oc * 27 + k]) : (US)0;
  } else if (gid < ZTOT + 18432 + 8192 + 1024 + 8192) {
    gap[gid - (ZTOT + 18432 + 8192 + 1024)] = 0.f;
  }
}

// ---------------------------------------------------------------------------
// K1: stem conv 3->32 via MFMA im2col (K=27 padded to 32 = 2 MFMAs/tile).
// Block = one (output row y, n): stage 3 input rows x 3ch f32 into LDS
// (+1-shifted, zero-padded); wave w owns px tile [32w,32w+32); per lane
// assemble A-frags (k -> ic,ky,kx) from LDS, B from wt0; D: lane=oc, reg=px;
// BN+ReLU -> bf16 -> LDS [px][32oc] -> parity-split full-chunk stores.
// Grid (120, 64). Replaces the f32-vector k1 (68us, VALU+LDS-read bound).
// ---------------------------------------------------------------------------
#define XSW 244
__global__ __launch_bounds__(256) void k1_mfma(
    const float* __restrict__ x, const US* __restrict__ wt0,
    const float* __restrict__ alpha, const float* __restrict__ beta,
    US* __restrict__ h1q) {
  __shared__ float xs[3 * 3 * XSW];   // [ic][r][244]: xs[..][i] = row[i-1]
  __shared__ US ot[128 * 32];         // [px][oc] bf16
  int y = blockIdx.x, n = blockIdx.y;
  int iy0 = 2 * y - 1;
  const float* xn = x + (long)n * C0_ * HW_ * HW_;
  for (int e = threadIdx.x; e < 3 * 3 * XSW; e += 256) {
    int w244 = e % XSW, rc = e / XSW;
    int ic = rc / 3, r = rc % 3;
    int iy = iy0 + r, ix = w244 - 1;
    float v = 0.f;
    if (iy >= 0 && ix >= 0 && ix < HW_)
      v = xn[(long)ic * HW_ * HW_ + iy * HW_ + ix];
    xs[e] = v;
  }
  __syncthreads();

  int t = threadIdx.x, wv = t >> 6, l = t & 63;
  int lane31 = l & 31, half = l >> 5;
  int ox = wv * 32 + lane31;
  int oxc = ox < H1_ ? ox : (H1_ - 1);

  // A fragments: k = m*16 + half*8 + j
  float fa[16];
#pragma unroll
  for (int m = 0; m < 2; m++)
#pragma unroll
    for (int j = 0; j < 8; j++) {
      int k = m * 16 + half * 8 + j;
      float v = 0.f;
      if (k < 27) {
        int ic = k / 9, rem = k - ic * 9;
        int ky = rem / 3, kx = rem - ky * 3;
        v = xs[(ic * 3 + ky) * XSW + 2 * oxc + kx];
      }
      fa[m * 8 + j] = v;
    }
  bf16x8 a0, a1;
#pragma unroll
  for (int j = 0; j < 8; j++) {
    a0[j] = (short)f2bf(fa[j]);
    a1[j] = (short)f2bf(fa[8 + j]);
  }
  const US* wb = wt0 + lane31 * 32 + half * 8;   // oc = lane31
  bf16x8 b0 = *(const bf16x8*)(wb);
  bf16x8 b1 = *(const bf16x8*)(wb + 16);

  f32x16 acc;
#pragma unroll
  for (int i = 0; i < 16; i++) acc[i] = 0.f;
  acc = __builtin_amdgcn_mfma_f32_32x32x16_bf16(a0, b0, acc, 0, 0, 0);
  acc = __builtin_amdgcn_mfma_f32_32x32x16_bf16(a1, b1, acc, 0, 0, 0);

  int oc = lane31;
  float al = alpha[oc], be = beta[oc];
#pragma unroll
  for (int r = 0; r < 16; r++) {
    int row = (r & 3) + 8 * (r >> 2) + 4 * half;   // px within tile
    float v = fmaxf(fmaf(acc[r], al, be), 0.f);
    ot[(wv * 32 + row) * 32 + oc] = f2bf(v);
  }
  __syncthreads();

  // store 120 px * 64 B as parity-split full chunks; 480 uint4 total
  long rowb = ((long)(n * 122 + y + 1)) * H1Q_ROW;
  for (int u = t; u < 480; u += 256) {
    int px = u >> 2, q = u & 3;
    int pl = px & 1;
    int m = (px + 1) >> 1;
    long addr = rowb + (pl ? H1Q_PL : 0) + (long)m * 32 + q * 8;
    *(uint4*)(h1q + addr) = *(const uint4*)(ot + px * 32 + q * 8);
  }
}

// ---------------------------------------------------------------------------
// K2: FUSED conv2 + conv3 + BN/ReLU + GAP, ILP-widened (R11 config).
// ---------------------------------------------------------------------------
#define TS 72
__global__ __launch_bounds__(256) void k2_fused(
    const US* __restrict__ h1q, const US* __restrict__ wt1,
    const US* __restrict__ wt2,
    const float* __restrict__ a1, const float* __restrict__ b1,
    const float* __restrict__ a2, const float* __restrict__ b2,
    float* __restrict__ gap) {
  __shared__ US tile[128 * TS];  // 18432 B
  int n = blockIdx.y, tileb = blockIdx.x;
  int t = threadIdx.x, w = t >> 6, l = t & 63;
  int wm = w & 1, wn = w >> 1;
  int lane31 = l & 31, half = l >> 5;
  int oc = wn * 32 + lane31;

  int pxb0 = tileb * 128 + wm * 64;
  int pxb1 = pxb0 + 32;
  int p0 = pxb0 + lane31; int pc0 = p0 < 3600 ? p0 : 3599;
  int p1 = pxb1 + lane31; int pc1 = p1 < 3600 ? p1 : 3599;
  int y0 = pc0 / 60, xx0 = pc0 % 60;
  int y1 = pc1 / 60, xx1 = pc1 % 60;

  f32x16 accA, accB;
#pragma unroll
  for (int i = 0; i < 16; i++) { accA[i] = 0.f; accB[i] = 0.f; }

#pragma unroll
  for (int ky = 0; ky < 3; ky++) {
    const US* c0a1 = h1q + ((long)(n * 122 + 2 * y0 + ky)) * H1Q_ROW
                         + (long)xx0 * 32 + half * 8;
    const US* c1a1 = h1q + ((long)(n * 122 + 2 * y1 + ky)) * H1Q_ROW
                         + (long)xx1 * 32 + half * 8;
    const US* wk = wt1 + (ky * 3) * (64 * 32) + oc * 32 + half * 8;
#pragma unroll
    for (int kx = 0; kx < 3; kx++) {
      long aoff = (kx == 1) ? 0 : (kx == 0 ? H1Q_PL : (H1Q_PL + 32));
      const US* bp = wk + kx * (64 * 32);
#pragma unroll
      for (int c = 0; c < 2; c++) {
        bf16x8 bv  = *(const bf16x8*)(bp + c * 16);
        bf16x8 av0 = *(const bf16x8*)(c0a1 + aoff + c * 16);
        bf16x8 av1 = *(const bf16x8*)(c1a1 + aoff + c * 16);
        accA = __builtin_amdgcn_mfma_f32_32x32x16_bf16(av0, bv, accA, 0, 0, 0);
        accB = __builtin_amdgcn_mfma_f32_32x32x16_bf16(av1, bv, accB, 0, 0, 0);
      }
    }
  }
  {
    float al = a1[oc], be = b1[oc];
#pragma unroll
    for (int r = 0; r < 16; r++) {
      int row = (r & 3) + 8 * (r >> 2) + 4 * half;
      float vA = fmaxf(fmaf(accA[r], al, be), 0.f);
      float vB = fmaxf(fmaf(accB[r], al, be), 0.f);
      tile[(wm * 64 + row) * TS + oc] = f2bf(vA);
      tile[(wm * 64 + 32 + row) * TS + oc] = f2bf(vB);
    }
  }
  __syncthreads();

  int base_px = tileb * 128 + w * 32;
  const US* abase2 = tile + (w * 32 + lane31) * TS + half * 8;
  bf16x8 af[4];
#pragma unroll
  for (int c = 0; c < 4; c++) af[c] = *(const bf16x8*)(abase2 + c * 16);

#pragma unroll
  for (int nt = 0; nt < 4; nt++) {
    int oc2 = nt * 32 + lane31;
    const US* bb = wt2 + oc2 * 64 + half * 8;
    f32x16 acc2;
#pragma unroll
    for (int i = 0; i < 16; i++) acc2[i] = 0.f;
#pragma unroll
    for (int c = 0; c < 4; c++) {
      bf16x8 bv = *(const bf16x8*)(bb + c * 16);
      acc2 = __builtin_amdgcn_mfma_f32_32x32x16_bf16(af[c], bv, acc2, 0, 0, 0);
    }
    float al2 = a2[oc2], be2 = b2[oc2];
    float s = 0.f;
    if (base_px + 31 < 3600) {
#pragma unroll
      for (int r = 0; r < 16; r++) s += fmaxf(fmaf(acc2[r], al2, be2), 0.f);
    } else {
#pragma unroll
      for (int r = 0; r < 16; r++) {
        int row = (r & 3) + 8 * (r >> 2) + 4 * half;
        if (base_px + row < 3600) s += fmaxf(fmaf(acc2[r], al2, be2), 0.f);
      }
    }
    s += __shfl_xor(s, 32);
    if (half == 0) atomicAdd(gap + n * C3_ + oc2, s);
  }
}

// ---------------------------------------------------------------------------
// K4: head — gap/3600 @ w_head^T, BN fold + ReLU (f32).
// ---------------------------------------------------------------------------
__global__ __launch_bounds__(256) void k4_head(
    const float* __restrict__ gap, const float* __restrict__ wh,
    const float* __restrict__ alpha, const float* __restrict__ beta,
    float* __restrict__ out) {
  __shared__ float g[C3_];
  int n = blockIdx.y;
  int o = blockIdx.x * 256 + threadIdx.x;
  if (threadIdx.x < C3_)
    g[threadIdx.x] = gap[n * C3_ + threadIdx.x] * (1.f / 3600.f);
  __syncthreads();
  const float* wr = wh + (long)o * C3_;
  float acc = 0.f;
#pragma unroll 8
  for (int c = 0; c < C3_; c += 4) {
    float4 wv = *(const float4*)(wr + c);
    acc = fmaf(wv.x, g[c],     acc);
    acc = fmaf(wv.y, g[c + 1], acc);
    acc = fmaf(wv.z, g[c + 2], acc);
    acc = fmaf(wv.w, g[c + 3], acc);
  }
  out[n * HEAD_ + o] = fmaxf(fmaf(acc, alpha[o], beta[o]), 0.f);
}

// ---------------------------------------------------------------------------
extern "C" void kernel_launch(void* const* d_in, const int* in_sizes, int n_in,
                              void* d_out, int out_size, void* d_ws,
                              size_t ws_size, hipStream_t stream) {
  const float* x      = (const float*)d_in[0];
  const float* w_stem = (const float*)d_in[1];
  const float* a_stem = (const float*)d_in[2];
  const float* b_stem = (const float*)d_in[3];
  const float* w1     = (const float*)d_in[4];
  const float* a1     = (const float*)d_in[5];
  const float* b1     = (const float*)d_in[6];
  const float* w2     = (const float*)d_in[7];
  const float* a2     = (const float*)d_in[8];
  const float* b2     = (const float*)d_in[9];
  const float* wh     = (const float*)d_in[10];
  const float* ah     = (const float*)d_in[11];
  const float* bh     = (const float*)d_in[12];
  float* out = (float*)d_out;

  US* h1q = (US*)d_ws;                                   // 64*122*3968
  US* wt1 = h1q + (size_t)N_ * 122 * H1Q_ROW;            // 9*64*32
  US* wt2 = wt1 + 9 * 64 * 32;                           // 128*64
  US* wt0 = wt2 + C3_ * C2_;                             // 32*32
  float* gap = (float*)(wt0 + 1024);                     // 64*128 f32

  {  // K0 prep
    int total = ZTOT + 18432 + 8192 + 1024 + 8192;
    k0_prep<<<(total + 255) / 256, 256, 0, stream>>>(w1, w2, w_stem, h1q,
                                                     wt1, wt2, wt0, gap);
  }
  {  // K1 MFMA stem: one block per (row, n)
    dim3 grid(H1_, N_);
    k1_mfma<<<grid, 256, 0, stream>>>(x, wt0, a_stem, b_stem, h1q);
  }
  {  // K2 fused conv2+conv3+GAP
    dim3 grid(29, N_);
    k2_fused<<<grid, 256, 0, stream>>>(h1q, wt1, wt2, a1, b1, a2, b2, gap);
  }
  {  // K4
    dim3 grid(HEAD_ / 256, N_);
    k4_head<<<grid, 256, 0, stream>>>(gap, wh, ah, bh, out);
  }
}